// Round 1
// baseline (451.317 us; speedup 1.0000x reference)
//
#include <hip/hip_runtime.h>
#include <hip/hip_bf16.h>

typedef __attribute__((ext_vector_type(8))) short bf8_t;          // 8 x bf16 (4 VGPR)
typedef __attribute__((ext_vector_type(4))) float f32x4;
typedef __attribute__((ext_vector_type(4))) unsigned short u16x4; // 8 B
typedef __attribute__((ext_vector_type(8))) unsigned short u16x8; // 16 B

#define DEVI static __device__ __forceinline__

DEVI unsigned short f2bf(float f) {
  union { __hip_bfloat16 h; unsigned short u; } cv;
  cv.h = __float2bfloat16(f);
  return cv.u;
}
DEVI float bf2f(unsigned short u) {
  union { __hip_bfloat16 h; unsigned short u; } cv;
  cv.u = u;
  return __bfloat162float(cv.h);
}

// ---------------- fp32 -> bf16 convert (vectorized) ----------------
__global__ void cvt_kernel(const float* __restrict__ src, unsigned short* __restrict__ dst, int n4) {
  int i = blockIdx.x * blockDim.x + threadIdx.x;
  if (i >= n4) return;
  float4 v = reinterpret_cast<const float4*>(src)[i];
  u16x4 o;
  o[0] = f2bf(v.x); o[1] = f2bf(v.y); o[2] = f2bf(v.z); o[3] = f2bf(v.w);
  reinterpret_cast<u16x4*>(dst)[i] = o;
}

// ---------------- bf16 GEMM: C[M,512] = A[M,512] @ W[512,512]^T + bias ----------------
// mode 0: write bf16 to [b,h,i,d] qkv layout; mode 1: write fp32 row-major [M,512]
__global__ __launch_bounds__(256) void gemm_bf16_kernel(
    const unsigned short* __restrict__ A, const unsigned short* __restrict__ W,
    const float* __restrict__ bias, unsigned short* __restrict__ out_bf,
    float* __restrict__ out_f32, int mode)
{
  const int m0 = blockIdx.x * 64;
  const int n0 = blockIdx.y * 64;
  const int w = threadIdx.x >> 6, L = threadIdx.x & 63;
  const int c = L & 15, g = L >> 4;
  const unsigned short* arow = A + (long long)(m0 + 16 * w + c) * 512 + 8 * g;
  const unsigned short* wrow = W + (long long)(n0 + c) * 512 + 8 * g;
  f32x4 acc0 = {0.f, 0.f, 0.f, 0.f}, acc1 = acc0, acc2 = acc0, acc3 = acc0;
#pragma unroll 4
  for (int kk = 0; kk < 16; ++kk) {
    bf8_t a  = *reinterpret_cast<const bf8_t*>(arow + 32 * kk);
    bf8_t b0 = *reinterpret_cast<const bf8_t*>(wrow + 32 * kk);
    bf8_t b1 = *reinterpret_cast<const bf8_t*>(wrow + 16 * 512 + 32 * kk);
    bf8_t b2 = *reinterpret_cast<const bf8_t*>(wrow + 32 * 512 + 32 * kk);
    bf8_t b3 = *reinterpret_cast<const bf8_t*>(wrow + 48 * 512 + 32 * kk);
    acc0 = __builtin_amdgcn_mfma_f32_16x16x32_bf16(a, b0, acc0, 0, 0, 0);
    acc1 = __builtin_amdgcn_mfma_f32_16x16x32_bf16(a, b1, acc1, 0, 0, 0);
    acc2 = __builtin_amdgcn_mfma_f32_16x16x32_bf16(a, b2, acc2, 0, 0, 0);
    acc3 = __builtin_amdgcn_mfma_f32_16x16x32_bf16(a, b3, acc3, 0, 0, 0);
  }
  f32x4 accs[4] = {acc0, acc1, acc2, acc3};
#pragma unroll
  for (int t = 0; t < 4; ++t) {
    int n = n0 + 16 * t + c;
    float bv = bias[n];
#pragma unroll
    for (int r = 0; r < 4; ++r) {
      int m = m0 + 16 * w + 4 * g + r;
      float v = accs[t][r] + bv;
      if (mode == 0) {
        int bb = m >> 10, ii = m & 1023, hh = n >> 6, dd = n & 63;
        out_bf[(((long long)(bb * 8 + hh)) * 1024 + ii) * 64 + dd] = f2bf(v);
      } else {
        out_f32[(long long)m * 512 + n] = v;
      }
    }
  }
}

// ---------------- inverse norms of q/k rows (64 elems each) ----------------
__global__ void invnorm_kernel(const unsigned short* __restrict__ qbf,
                               const unsigned short* __restrict__ kbf,
                               float* __restrict__ iq, float* __restrict__ ik)
{
  int row = blockIdx.x * 4 + (threadIdx.x >> 6); // 0..131071
  int lane = threadIdx.x & 63;
  const unsigned short* src = (row < 65536) ? qbf : kbf;
  int r = row & 65535;
  float v = bf2f(src[(long long)r * 64 + lane]);
  float s = v * v;
#pragma unroll
  for (int off = 1; off < 64; off <<= 1) s += __shfl_xor(s, off, 64);
  if (lane == 0) ((row < 65536) ? iq : ik)[r] = rsqrtf(s);
}

// ---------------- V transpose: vt[b,h,d,j] = v[b,h,j,d] ----------------
__global__ void transpose_v_kernel(const unsigned short* __restrict__ vbf,
                                   unsigned short* __restrict__ vt)
{
  __shared__ unsigned short ts[64][72];
  int bh = blockIdx.x, j0 = blockIdx.y * 64;
  int t = threadIdx.x;
  int jl = t >> 2, db = (t & 3) * 16;
  const unsigned short* src = vbf + ((long long)bh * 1024 + j0 + jl) * 64 + db;
  u16x8 v0 = *reinterpret_cast<const u16x8*>(src);
  u16x8 v1 = *reinterpret_cast<const u16x8*>(src + 8);
#pragma unroll
  for (int e = 0; e < 8; ++e) { ts[jl][db + e] = v0[e]; ts[jl][db + 8 + e] = v1[e]; }
  __syncthreads();
  int d = t >> 2, jb = (t & 3) * 16;
  u16x8 o0, o1;
#pragma unroll
  for (int e = 0; e < 8; ++e) { o0[e] = ts[jb + e][d]; o1[e] = ts[jb + 8 + e][d]; }
  unsigned short* dst = vt + ((long long)bh * 64 + d) * 1024 + j0 + jb;
  *reinterpret_cast<u16x8*>(dst) = o0;
  *reinterpret_cast<u16x8*>(dst + 8) = o1;
}

// ---------------- fused: QK^T (MFMA) + cosine + mask + softmax + attn + loss partials ----------------
// grid 512 = (b, i-tile of 16 rows); block 256; wave w owns j in [256w, 256w+256)
__global__ __launch_bounds__(256, 2) void fused_attn_kernel(
    const unsigned short* __restrict__ qbf, const unsigned short* __restrict__ kbf,
    const float* __restrict__ mask, const float* __restrict__ iqn,
    const float* __restrict__ ikn, float* __restrict__ attn_out,
    float* __restrict__ partials)
{
  __shared__ float redA[4][16], redB[4][16], redN[4][16], redD[4][16], redE[4];
  const int blk = blockIdx.x;
  const int b = blk >> 6, i0 = (blk & 63) * 16;
  const int w = threadIdx.x >> 6, L = threadIdx.x & 63;
  const int c = L & 15, g = L >> 4;
  const int j0 = 256 * w;

  // mask bits (reused by all heads) + |eye - mask| accumulation
  unsigned long long mbits = 0ull;
  float eyeacc = 0.f;
#pragma unroll
  for (int jt = 0; jt < 16; ++jt) {
    int j = j0 + 16 * jt + c;
    const float* mp = mask + ((long long)b * 1024 + i0 + 4 * g) * 1024 + j;
#pragma unroll
    for (int r = 0; r < 4; ++r) {
      float m = mp[(long long)r * 1024];
      int i = i0 + 4 * g + r;
      mbits |= (unsigned long long)(m != 0.0f) << (jt * 4 + r);
      eyeacc += fabsf(((i == j) ? 1.0f : 0.0f) - m);
    }
  }

  float cosa[16][4];
#pragma unroll
  for (int jt = 0; jt < 16; ++jt)
#pragma unroll
    for (int r = 0; r < 4; ++r) cosa[jt][r] = 0.f;

  for (int h = 0; h < 8; ++h) {
    const unsigned short* qh = qbf + (((long long)b * 8 + h) * 1024) * 64;
    const unsigned short* kh = kbf + (((long long)b * 8 + h) * 1024) * 64;
    bf8_t a0 = *reinterpret_cast<const bf8_t*>(qh + (i0 + c) * 64 + 8 * g);
    bf8_t a1 = *reinterpret_cast<const bf8_t*>(qh + (i0 + c) * 64 + 32 + 8 * g);
    f32x4 sc[16];
#pragma unroll
    for (int jt = 0; jt < 16; ++jt) {
      const unsigned short* kp = kh + (j0 + 16 * jt + c) * 64 + 8 * g;
      bf8_t b0 = *reinterpret_cast<const bf8_t*>(kp);
      bf8_t b1 = *reinterpret_cast<const bf8_t*>(kp + 32);
      f32x4 acc = {0.f, 0.f, 0.f, 0.f};
      acc = __builtin_amdgcn_mfma_f32_16x16x32_bf16(a0, b0, acc, 0, 0, 0);
      acc = __builtin_amdgcn_mfma_f32_16x16x32_bf16(a1, b1, acc, 0, 0, 0);
      sc[jt] = acc;
    }
    // cosine accumulate (raw scores), then masked logits + row max
    float iq[4];
    const float* iqp = iqn + ((long long)b * 8 + h) * 1024 + i0 + 4 * g;
#pragma unroll
    for (int r = 0; r < 4; ++r) iq[r] = iqp[r];
    const float* ikp = ikn + ((long long)b * 8 + h) * 1024 + j0 + c;
    float rmax[4] = {-1e30f, -1e30f, -1e30f, -1e30f};
#pragma unroll
    for (int jt = 0; jt < 16; ++jt) {
      float ik = ikp[16 * jt];
#pragma unroll
      for (int r = 0; r < 4; ++r) {
        float s = sc[jt][r];
        cosa[jt][r] += s * iq[r] * ik;
        float lg = ((mbits >> (jt * 4 + r)) & 1ull) ? s * 0.125f
                                                    : -2.8782313662425572f; // LARGE_NEG*scale
        sc[jt][r] = lg;
        rmax[r] = fmaxf(rmax[r], lg);
      }
    }
#pragma unroll
    for (int r = 0; r < 4; ++r) {
#pragma unroll
      for (int off = 1; off < 16; off <<= 1)
        rmax[r] = fmaxf(rmax[r], __shfl_xor(rmax[r], off, 64));
    }
    if (c == 0) {
#pragma unroll
      for (int r = 0; r < 4; ++r) redA[w][4 * g + r] = rmax[r];
    }
    __syncthreads();
    float rowmax[4];
#pragma unroll
    for (int r = 0; r < 4; ++r)
      rowmax[r] = fmaxf(fmaxf(redA[0][4 * g + r], redA[1][4 * g + r]),
                        fmaxf(redA[2][4 * g + r], redA[3][4 * g + r]));
    float rsum[4] = {0.f, 0.f, 0.f, 0.f};
#pragma unroll
    for (int jt = 0; jt < 16; ++jt) {
#pragma unroll
      for (int r = 0; r < 4; ++r) {
        float p = __expf(sc[jt][r] - rowmax[r]);
        sc[jt][r] = p;
        rsum[r] += p;
      }
    }
#pragma unroll
    for (int r = 0; r < 4; ++r) {
#pragma unroll
      for (int off = 1; off < 16; off <<= 1) rsum[r] += __shfl_xor(rsum[r], off, 64);
    }
    if (c == 0) {
#pragma unroll
      for (int r = 0; r < 4; ++r) redB[w][4 * g + r] = rsum[r];
    }
    __syncthreads();
    float rinv[4];
#pragma unroll
    for (int r = 0; r < 4; ++r)
      rinv[r] = 1.0f / (redB[0][4 * g + r] + redB[1][4 * g + r] +
                        redB[2][4 * g + r] + redB[3][4 * g + r]);
    float* ao = attn_out + (((long long)b * 8 + h) * 1024) * 1024;
#pragma unroll
    for (int jt = 0; jt < 16; ++jt) {
      int j = j0 + 16 * jt + c;
#pragma unroll
      for (int r = 0; r < 4; ++r)
        ao[(long long)(i0 + 4 * g + r) * 1024 + j] = sc[jt][r] * rinv[r];
    }
    __syncthreads(); // protect redA/redB for next head
  }

  // contrastive loss: e = exp(cosa/H / TEMP) = exp(cosa * 1.25)
  float num[4] = {0.f, 0.f, 0.f, 0.f}, den[4] = {0.f, 0.f, 0.f, 0.f};
#pragma unroll
  for (int jt = 0; jt < 16; ++jt) {
#pragma unroll
    for (int r = 0; r < 4; ++r) {
      float e = __expf(cosa[jt][r] * 1.25f);
      den[r] += e;
      num[r] += ((mbits >> (jt * 4 + r)) & 1ull) ? e : 0.f;
    }
  }
#pragma unroll
  for (int r = 0; r < 4; ++r) {
#pragma unroll
    for (int off = 1; off < 16; off <<= 1) {
      num[r] += __shfl_xor(num[r], off, 64);
      den[r] += __shfl_xor(den[r], off, 64);
    }
  }
  if (c == 0) {
#pragma unroll
    for (int r = 0; r < 4; ++r) { redN[w][4 * g + r] = num[r]; redD[w][4 * g + r] = den[r]; }
  }
  float es = eyeacc;
#pragma unroll
  for (int off = 1; off < 64; off <<= 1) es += __shfl_xor(es, off, 64);
  if (L == 0) redE[w] = es;
  __syncthreads();
  if (w == 0) {
    float cl = 0.f;
    if (L < 16) {
      float dn = redD[0][L] + redD[1][L] + redD[2][L] + redD[3][L];
      float nm = redN[0][L] + redN[1][L] + redN[2][L] + redN[3][L];
      cl = __logf(dn) - __logf(nm);
    }
#pragma unroll
    for (int off = 1; off < 64; off <<= 1) cl += __shfl_xor(cl, off, 64);
    if (L == 0) {
      float eyeT = redE[0] + redE[1] + redE[2] + redE[3];
      partials[blk] = cl * (1.0f / 8192.0f) + eyeT * (float)(0.3 / 8380416.0);
    }
  }
}

// ---------------- PV: inter[b,i,h*64+d] = sum_j attn[b,h,i,j] * v[b,h,j,d] ----------------
__global__ __launch_bounds__(256) void pv_kernel(
    const float* __restrict__ attn, const unsigned short* __restrict__ vt,
    unsigned short* __restrict__ inter)
{
  const int bh = blockIdx.x;
  const int w = threadIdx.x >> 6, L = threadIdx.x & 63;
  const int c = L & 15, g = L >> 4;
  const int i0 = blockIdx.y * 64 + w * 16;
  const float* ap = attn + ((long long)bh * 1024 + i0 + c) * 1024 + 8 * g;
  const unsigned short* vp = vt + (long long)bh * 64 * 1024 + 8 * g;
  f32x4 acc0 = {0.f, 0.f, 0.f, 0.f}, acc1 = acc0, acc2 = acc0, acc3 = acc0;
#pragma unroll 2
  for (int ks = 0; ks < 32; ++ks) {
    const float* a8 = ap + 32 * ks;
    float4 lo = *reinterpret_cast<const float4*>(a8);
    float4 hi = *reinterpret_cast<const float4*>(a8 + 4);
    bf8_t af;
    af[0] = (short)f2bf(lo.x); af[1] = (short)f2bf(lo.y);
    af[2] = (short)f2bf(lo.z); af[3] = (short)f2bf(lo.w);
    af[4] = (short)f2bf(hi.x); af[5] = (short)f2bf(hi.y);
    af[6] = (short)f2bf(hi.z); af[7] = (short)f2bf(hi.w);
    bf8_t b0 = *reinterpret_cast<const bf8_t*>(vp + (long long)(c) * 1024 + 32 * ks);
    bf8_t b1 = *reinterpret_cast<const bf8_t*>(vp + (long long)(16 + c) * 1024 + 32 * ks);
    bf8_t b2 = *reinterpret_cast<const bf8_t*>(vp + (long long)(32 + c) * 1024 + 32 * ks);
    bf8_t b3 = *reinterpret_cast<const bf8_t*>(vp + (long long)(48 + c) * 1024 + 32 * ks);
    acc0 = __builtin_amdgcn_mfma_f32_16x16x32_bf16(af, b0, acc0, 0, 0, 0);
    acc1 = __builtin_amdgcn_mfma_f32_16x16x32_bf16(af, b1, acc1, 0, 0, 0);
    acc2 = __builtin_amdgcn_mfma_f32_16x16x32_bf16(af, b2, acc2, 0, 0, 0);
    acc3 = __builtin_amdgcn_mfma_f32_16x16x32_bf16(af, b3, acc3, 0, 0, 0);
  }
  f32x4 accs[4] = {acc0, acc1, acc2, acc3};
  int b = bh >> 3, h = bh & 7;
#pragma unroll
  for (int t = 0; t < 4; ++t) {
#pragma unroll
    for (int r = 0; r < 4; ++r) {
      inter[((long long)b * 1024 + i0 + 4 * g + r) * 512 + h * 64 + 16 * t + c] =
          f2bf(accs[t][r]);
    }
  }
}

// ---------------- deterministic loss reduction ----------------
__global__ void loss_reduce_kernel(const float* __restrict__ partials, float* __restrict__ out) {
  int t = threadIdx.x;
  float s = partials[t] + partials[t + 256];
#pragma unroll
  for (int off = 1; off < 64; off <<= 1) s += __shfl_xor(s, off, 64);
  __shared__ float red[4];
  if ((t & 63) == 0) red[t >> 6] = s;
  __syncthreads();
  if (t == 0) out[0] = red[0] + red[1] + red[2] + red[3];
}

extern "C" void kernel_launch(void* const* d_in, const int* in_sizes, int n_in,
                              void* d_out, int out_size, void* d_ws, size_t ws_size,
                              hipStream_t stream)
{
  const float* x    = (const float*)d_in[0];
  const float* mask = (const float*)d_in[1];
  const float* wq = (const float*)d_in[2]; const float* bq = (const float*)d_in[3];
  const float* wk = (const float*)d_in[4]; const float* bk = (const float*)d_in[5];
  const float* wv = (const float*)d_in[6]; const float* bv = (const float*)d_in[7];
  const float* wo = (const float*)d_in[8]; const float* bo = (const float*)d_in[9];

  unsigned short* x_bf  = (unsigned short*)d_ws;          // 8192*512
  unsigned short* wq_bf = x_bf + 8192 * 512;
  unsigned short* wk_bf = wq_bf + 512 * 512;
  unsigned short* wv_bf = wk_bf + 512 * 512;
  unsigned short* wo_bf = wv_bf + 512 * 512;
  unsigned short* q_bf  = wo_bf + 512 * 512;              // 4 M each below
  unsigned short* k_bf  = q_bf + 4194304;
  unsigned short* v_bf  = k_bf + 4194304;
  unsigned short* vt_bf = v_bf + 4194304;
  unsigned short* in_bf = vt_bf + 4194304;
  float* iqn   = (float*)(in_bf + 4194304);
  float* ikn   = iqn + 65536;
  float* parts = ikn + 65536;

  float* out_f  = (float*)d_out;
  float* attn_o = out_f + 4194304;
  float* loss_o = attn_o + 67108864;

  cvt_kernel<<<4096, 256, 0, stream>>>(x, x_bf, 1048576);
  cvt_kernel<<<256, 256, 0, stream>>>(wq, wq_bf, 65536);
  cvt_kernel<<<256, 256, 0, stream>>>(wk, wk_bf, 65536);
  cvt_kernel<<<256, 256, 0, stream>>>(wv, wv_bf, 65536);
  cvt_kernel<<<256, 256, 0, stream>>>(wo, wo_bf, 65536);

  dim3 gg(128, 8);
  gemm_bf16_kernel<<<gg, 256, 0, stream>>>(x_bf, wq_bf, bq, q_bf, nullptr, 0);
  gemm_bf16_kernel<<<gg, 256, 0, stream>>>(x_bf, wk_bf, bk, k_bf, nullptr, 0);
  gemm_bf16_kernel<<<gg, 256, 0, stream>>>(x_bf, wv_bf, bv, v_bf, nullptr, 0);

  invnorm_kernel<<<32768, 256, 0, stream>>>(q_bf, k_bf, iqn, ikn);
  transpose_v_kernel<<<dim3(64, 16), 256, 0, stream>>>(v_bf, vt_bf);

  fused_attn_kernel<<<512, 256, 0, stream>>>(q_bf, k_bf, mask, iqn, ikn, attn_o, parts);

  pv_kernel<<<dim3(64, 16), 256, 0, stream>>>(attn_o, vt_bf, in_bf);

  gemm_bf16_kernel<<<gg, 256, 0, stream>>>(in_bf, wo_bf, bo, nullptr, out_f, 1);

  loss_reduce_kernel<<<1, 256, 0, stream>>>(parts, loss_o);
}

// Round 2
// 398.875 us; speedup vs baseline: 1.1315x; 1.1315x over previous
//
#include <hip/hip_runtime.h>
#include <hip/hip_bf16.h>

typedef __attribute__((ext_vector_type(8))) short bf8_t;          // 8 x bf16
typedef __attribute__((ext_vector_type(4))) float f32x4;
typedef __attribute__((ext_vector_type(4))) unsigned short u16x4;
typedef __attribute__((ext_vector_type(8))) unsigned short u16x8;

#define DEVI static __device__ __forceinline__

DEVI unsigned short f2bf(float f) {
  union { __hip_bfloat16 h; unsigned short u; } cv;
  cv.h = __float2bfloat16(f);
  return cv.u;
}
DEVI float bf2f(unsigned short u) {
  union { __hip_bfloat16 h; unsigned short u; } cv;
  cv.u = u;
  return __bfloat162float(cv.h);
}

// ---------------- fp32 -> bf16 convert ----------------
__global__ void cvt_kernel(const float* __restrict__ src, unsigned short* __restrict__ dst, int n4) {
  int i = blockIdx.x * blockDim.x + threadIdx.x;
  if (i >= n4) return;
  float4 v = reinterpret_cast<const float4*>(src)[i];
  u16x4 o;
  o[0] = f2bf(v.x); o[1] = f2bf(v.y); o[2] = f2bf(v.z); o[3] = f2bf(v.w);
  reinterpret_cast<u16x4*>(dst)[i] = o;
}

// ---------------- QKV projection GEMM + fused q/k row-norm epilogue ----------------
__global__ __launch_bounds__(256) void qkv_gemm_kernel(
    const unsigned short* __restrict__ x_bf,
    const unsigned short* __restrict__ wq_bf, const unsigned short* __restrict__ wk_bf,
    const unsigned short* __restrict__ wv_bf,
    const float* __restrict__ bq, const float* __restrict__ bk, const float* __restrict__ bv,
    unsigned short* __restrict__ q_bf, unsigned short* __restrict__ k_bf,
    unsigned short* __restrict__ v_bf, float* __restrict__ iqn, float* __restrict__ ikn)
{
  const int m0 = blockIdx.x * 64;
  const int nt = blockIdx.y;
  const int p = nt >> 3, h = nt & 7, n0 = h * 64;
  const unsigned short* W = (p == 0) ? wq_bf : (p == 1) ? wk_bf : wv_bf;
  const float* bias = (p == 0) ? bq : (p == 1) ? bk : bv;
  unsigned short* dst = (p == 0) ? q_bf : (p == 1) ? k_bf : v_bf;
  const int w = threadIdx.x >> 6, L = threadIdx.x & 63, c = L & 15, g = L >> 4;
  const unsigned short* arow = x_bf + (long long)(m0 + 16 * w + c) * 512 + 8 * g;
  const unsigned short* wrow = W + (long long)(n0 + c) * 512 + 8 * g;
  f32x4 acc0 = {0.f, 0.f, 0.f, 0.f}, acc1 = acc0, acc2 = acc0, acc3 = acc0;
#pragma unroll 4
  for (int kk = 0; kk < 16; ++kk) {
    bf8_t a  = *reinterpret_cast<const bf8_t*>(arow + 32 * kk);
    bf8_t b0 = *reinterpret_cast<const bf8_t*>(wrow + 32 * kk);
    bf8_t b1 = *reinterpret_cast<const bf8_t*>(wrow + 16 * 512 + 32 * kk);
    bf8_t b2 = *reinterpret_cast<const bf8_t*>(wrow + 32 * 512 + 32 * kk);
    bf8_t b3 = *reinterpret_cast<const bf8_t*>(wrow + 48 * 512 + 32 * kk);
    acc0 = __builtin_amdgcn_mfma_f32_16x16x32_bf16(a, b0, acc0, 0, 0, 0);
    acc1 = __builtin_amdgcn_mfma_f32_16x16x32_bf16(a, b1, acc1, 0, 0, 0);
    acc2 = __builtin_amdgcn_mfma_f32_16x16x32_bf16(a, b2, acc2, 0, 0, 0);
    acc3 = __builtin_amdgcn_mfma_f32_16x16x32_bf16(a, b3, acc3, 0, 0, 0);
  }
  f32x4 accs[4] = {acc0, acc1, acc2, acc3};
  float nacc[4] = {0.f, 0.f, 0.f, 0.f};
#pragma unroll
  for (int t = 0; t < 4; ++t) {
    float bvt = bias[n0 + 16 * t + c];
#pragma unroll
    for (int r = 0; r < 4; ++r) {
      int m = m0 + 16 * w + 4 * g + r;
      unsigned short ub = f2bf(accs[t][r] + bvt);
      int bb = m >> 10, ii = m & 1023;
      dst[(((long long)(bb * 8 + h)) * 1024 + ii) * 64 + 16 * t + c] = ub;
      float vr = bf2f(ub);
      nacc[r] += vr * vr;
    }
  }
  if (p < 2) {
#pragma unroll
    for (int r = 0; r < 4; ++r) {
#pragma unroll
      for (int off = 1; off < 16; off <<= 1) nacc[r] += __shfl_xor(nacc[r], off, 64);
    }
    if (c == 0) {
      float* dn = (p == 0) ? iqn : ikn;
#pragma unroll
      for (int r = 0; r < 4; ++r) {
        int m = m0 + 16 * w + 4 * g + r;
        dn[((long long)(m >> 10) * 8 + h) * 1024 + (m & 1023)] = rsqrtf(nacc[r]);
      }
    }
  }
}

// ---------------- V transpose: vt[b,h,d,j] = v[b,h,j,d] ----------------
__global__ void transpose_v_kernel(const unsigned short* __restrict__ vbf,
                                   unsigned short* __restrict__ vt)
{
  __shared__ unsigned short ts[64][72];
  int bh = blockIdx.x, j0 = blockIdx.y * 64;
  int t = threadIdx.x;
  int jl = t >> 2, db = (t & 3) * 16;
  const unsigned short* src = vbf + ((long long)bh * 1024 + j0 + jl) * 64 + db;
  u16x8 v0 = *reinterpret_cast<const u16x8*>(src);
  u16x8 v1 = *reinterpret_cast<const u16x8*>(src + 8);
#pragma unroll
  for (int e = 0; e < 8; ++e) { ts[jl][db + e] = v0[e]; ts[jl][db + 8 + e] = v1[e]; }
  __syncthreads();
  int d = t >> 2, jb = (t & 3) * 16;
  u16x8 o0, o1;
#pragma unroll
  for (int e = 0; e < 8; ++e) { o0[e] = ts[jb + e][d]; o1[e] = ts[jb + 8 + e][d]; }
  unsigned short* dst = vt + ((long long)bh * 64 + d) * 1024 + j0 + jb;
  *reinterpret_cast<u16x8*>(dst) = o0;
  *reinterpret_cast<u16x8*>(dst + 8) = o1;
}

// ---------------- mega: QK^T + cosine + softmax + attn + PV + out-proj + loss ----------------
#define P_STRIDE 1044
#define O_STRIDE 520
__global__ __launch_bounds__(256, 2) void mega_attn_kernel(
    const unsigned short* __restrict__ qbf, const unsigned short* __restrict__ kbf,
    const float* __restrict__ mask, const float* __restrict__ iqn,
    const float* __restrict__ ikn, const unsigned short* __restrict__ vt,
    const unsigned short* __restrict__ wo_bf, const float* __restrict__ bo,
    float* __restrict__ attn_out, float* __restrict__ out_f, float* __restrict__ partials)
{
  __shared__ unsigned short P_lds[16 * P_STRIDE];   // 33.4 KB
  __shared__ unsigned short O_lds[16 * O_STRIDE];   // 16.6 KB
  __shared__ float redM[4][16], redS[4][16], redN[4][16], redD[4][16], redE[4];
  const int blk = blockIdx.x;
  const int b = blk >> 6, i0 = (blk & 63) * 16;
  const int w = threadIdx.x >> 6, L = threadIdx.x & 63, c = L & 15, g = L >> 4;
  const int j0 = 256 * w;

  unsigned long long mbits = 0ull;
  float eyeacc = 0.f;
#pragma unroll
  for (int jt = 0; jt < 16; ++jt) {
    int j = j0 + 16 * jt + c;
    const float* mp = mask + ((long long)b * 1024 + i0 + 4 * g) * 1024 + j;
#pragma unroll
    for (int r = 0; r < 4; ++r) {
      float m = mp[(long long)r * 1024];
      int i = i0 + 4 * g + r;
      mbits |= (unsigned long long)(m != 0.0f) << (jt * 4 + r);
      eyeacc += fabsf(((i == j) ? 1.0f : 0.0f) - m);
    }
  }

  float cosa[16][4];
#pragma unroll
  for (int jt = 0; jt < 16; ++jt)
#pragma unroll
    for (int r = 0; r < 4; ++r) cosa[jt][r] = 0.f;

  for (int h = 0; h < 8; ++h) {
    const long long bh = (long long)b * 8 + h;
    const unsigned short* qh = qbf + bh * 65536;
    const unsigned short* kh = kbf + bh * 65536;
    bf8_t a0 = *reinterpret_cast<const bf8_t*>(qh + (i0 + c) * 64 + 8 * g);
    bf8_t a1 = *reinterpret_cast<const bf8_t*>(qh + (i0 + c) * 64 + 32 + 8 * g);
    f32x4 sc[16];
#pragma unroll
    for (int jt = 0; jt < 16; ++jt) {
      const unsigned short* kp = kh + (j0 + 16 * jt + c) * 64 + 8 * g;
      f32x4 acc = {0.f, 0.f, 0.f, 0.f};
      acc = __builtin_amdgcn_mfma_f32_16x16x32_bf16(a0, *reinterpret_cast<const bf8_t*>(kp), acc, 0, 0, 0);
      acc = __builtin_amdgcn_mfma_f32_16x16x32_bf16(a1, *reinterpret_cast<const bf8_t*>(kp + 32), acc, 0, 0, 0);
      sc[jt] = acc;
    }
    float iq[4];
    const float* iqp = iqn + bh * 1024 + i0 + 4 * g;
#pragma unroll
    for (int r = 0; r < 4; ++r) iq[r] = iqp[r];
    const float* ikp = ikn + bh * 1024 + j0 + c;
    float rmax[4] = {-1e30f, -1e30f, -1e30f, -1e30f};
#pragma unroll
    for (int jt = 0; jt < 16; ++jt) {
      float ik = ikp[16 * jt];
#pragma unroll
      for (int r = 0; r < 4; ++r) {
        float s = sc[jt][r];
        cosa[jt][r] += s * iq[r] * ik;
        float lg = ((mbits >> (jt * 4 + r)) & 1ull) ? s * 0.125f
                                                    : -2.8782313662425572f; // LARGE_NEG*scale
        sc[jt][r] = lg;
        rmax[r] = fmaxf(rmax[r], lg);
      }
    }
#pragma unroll
    for (int r = 0; r < 4; ++r) {
#pragma unroll
      for (int off = 1; off < 16; off <<= 1)
        rmax[r] = fmaxf(rmax[r], __shfl_xor(rmax[r], off, 64));
    }
    float rsum[4] = {0.f, 0.f, 0.f, 0.f};
#pragma unroll
    for (int jt = 0; jt < 16; ++jt) {
#pragma unroll
      for (int r = 0; r < 4; ++r) {
        float e = __expf(sc[jt][r] - rmax[r]);
        sc[jt][r] = e;
        rsum[r] += e;
      }
    }
#pragma unroll
    for (int r = 0; r < 4; ++r) {
#pragma unroll
      for (int off = 1; off < 16; off <<= 1) rsum[r] += __shfl_xor(rsum[r], off, 64);
    }
    if (c == 0) {
#pragma unroll
      for (int r = 0; r < 4; ++r) { redM[w][4 * g + r] = rmax[r]; redS[w][4 * g + r] = rsum[r]; }
    }
    __syncthreads();  // B1
    float scale[4];
#pragma unroll
    for (int r = 0; r < 4; ++r) {
      int row = 4 * g + r;
      float m0v = redM[0][row], m1v = redM[1][row], m2v = redM[2][row], m3v = redM[3][row];
      float M = fmaxf(fmaxf(m0v, m1v), fmaxf(m2v, m3v));
      float den = redS[0][row] * __expf(m0v - M) + redS[1][row] * __expf(m1v - M) +
                  redS[2][row] * __expf(m2v - M) + redS[3][row] * __expf(m3v - M);
      scale[r] = __expf(rmax[r] - M) / den;
    }
#pragma unroll
    for (int jt = 0; jt < 16; ++jt) {
#pragma unroll
      for (int r = 0; r < 4; ++r)
        P_lds[(4 * g + r) * P_STRIDE + j0 + 16 * jt + c] = f2bf(sc[jt][r] * scale[r]);
    }
    __syncthreads();  // B2
    {
      const unsigned short* vp = vt + (bh * 64 + 16 * w + c) * 1024;
      f32x4 oacc = {0.f, 0.f, 0.f, 0.f};
#pragma unroll
      for (int ks = 0; ks < 32; ++ks) {
        bf8_t pa = *reinterpret_cast<const bf8_t*>(P_lds + c * P_STRIDE + 32 * ks + 8 * g);
        bf8_t vb = *reinterpret_cast<const bf8_t*>(vp + 32 * ks + 8 * g);
        oacc = __builtin_amdgcn_mfma_f32_16x16x32_bf16(pa, vb, oacc, 0, 0, 0);
      }
#pragma unroll
      for (int r = 0; r < 4; ++r)
        O_lds[(4 * g + r) * O_STRIDE + h * 64 + 16 * w + c] = f2bf(oacc[r]);
      float* ao = attn_out + (bh * 1024 + i0) * 1024;
#pragma unroll
      for (int rr = 0; rr < 4; ++rr) {
        int row = 4 * w + rr;
        const unsigned short* pr = P_lds + row * P_STRIDE;
        u16x8 h0 = *reinterpret_cast<const u16x8*>(pr + 8 * L);
        u16x8 h1 = *reinterpret_cast<const u16x8*>(pr + 512 + 8 * L);
        float* aorow = ao + (long long)row * 1024;
        f32x4 f0, f1, f2, f3;
#pragma unroll
        for (int e = 0; e < 4; ++e) {
          f0[e] = bf2f(h0[e]); f1[e] = bf2f(h0[4 + e]);
          f2[e] = bf2f(h1[e]); f3[e] = bf2f(h1[4 + e]);
        }
        *reinterpret_cast<f32x4*>(aorow + 8 * L) = f0;
        *reinterpret_cast<f32x4*>(aorow + 8 * L + 4) = f1;
        *reinterpret_cast<f32x4*>(aorow + 512 + 8 * L) = f2;
        *reinterpret_cast<f32x4*>(aorow + 512 + 8 * L + 4) = f3;
      }
    }
  }

  float num[4] = {0.f, 0.f, 0.f, 0.f}, den4[4] = {0.f, 0.f, 0.f, 0.f};
#pragma unroll
  for (int jt = 0; jt < 16; ++jt) {
#pragma unroll
    for (int r = 0; r < 4; ++r) {
      float e = __expf(cosa[jt][r] * 1.25f);
      den4[r] += e;
      num[r] += ((mbits >> (jt * 4 + r)) & 1ull) ? e : 0.f;
    }
  }
#pragma unroll
  for (int r = 0; r < 4; ++r) {
#pragma unroll
    for (int off = 1; off < 16; off <<= 1) {
      num[r] += __shfl_xor(num[r], off, 64);
      den4[r] += __shfl_xor(den4[r], off, 64);
    }
  }
  if (c == 0) {
#pragma unroll
    for (int r = 0; r < 4; ++r) { redN[w][4 * g + r] = num[r]; redD[w][4 * g + r] = den4[r]; }
  }
  float es = eyeacc;
#pragma unroll
  for (int off = 1; off < 64; off <<= 1) es += __shfl_xor(es, off, 64);
  if (L == 0) redE[w] = es;
  __syncthreads();  // orders O_lds writes before out-proj reads; redN/redD for w0

  {
    const int n0w = 128 * w;
    f32x4 po[8];
#pragma unroll
    for (int t = 0; t < 8; ++t) po[t] = f32x4{0.f, 0.f, 0.f, 0.f};
#pragma unroll
    for (int ks = 0; ks < 16; ++ks) {
      bf8_t oa = *reinterpret_cast<const bf8_t*>(O_lds + c * O_STRIDE + 32 * ks + 8 * g);
#pragma unroll
      for (int t = 0; t < 8; ++t) {
        bf8_t wb = *reinterpret_cast<const bf8_t*>(wo_bf + (long long)(n0w + 16 * t + c) * 512 + 32 * ks + 8 * g);
        po[t] = __builtin_amdgcn_mfma_f32_16x16x32_bf16(oa, wb, po[t], 0, 0, 0);
      }
    }
#pragma unroll
    for (int t = 0; t < 8; ++t) {
      int n = n0w + 16 * t + c;
      float bv = bo[n];
#pragma unroll
      for (int r = 0; r < 4; ++r)
        out_f[((long long)b * 1024 + i0 + 4 * g + r) * 512 + n] = po[t][r] + bv;
    }
  }

  if (w == 0) {
    float cl = 0.f;
    if (L < 16) {
      float dn = redD[0][L] + redD[1][L] + redD[2][L] + redD[3][L];
      float nm = redN[0][L] + redN[1][L] + redN[2][L] + redN[3][L];
      cl = __logf(dn) - __logf(nm);
    }
#pragma unroll
    for (int off = 1; off < 64; off <<= 1) cl += __shfl_xor(cl, off, 64);
    if (L == 0) {
      float eyeT = redE[0] + redE[1] + redE[2] + redE[3];
      partials[blk] = cl * (1.0f / 8192.0f) + eyeT * (float)(0.3 / 8380416.0);
    }
  }
}

// ---------------- deterministic loss reduction ----------------
__global__ void loss_reduce_kernel(const float* __restrict__ partials, float* __restrict__ out) {
  int t = threadIdx.x;
  float s = partials[t] + partials[t + 256];
#pragma unroll
  for (int off = 1; off < 64; off <<= 1) s += __shfl_xor(s, off, 64);
  __shared__ float red[4];
  if ((t & 63) == 0) red[t >> 6] = s;
  __syncthreads();
  if (t == 0) out[0] = red[0] + red[1] + red[2] + red[3];
}

extern "C" void kernel_launch(void* const* d_in, const int* in_sizes, int n_in,
                              void* d_out, int out_size, void* d_ws, size_t ws_size,
                              hipStream_t stream)
{
  const float* x    = (const float*)d_in[0];
  const float* mask = (const float*)d_in[1];
  const float* wq = (const float*)d_in[2]; const float* bq = (const float*)d_in[3];
  const float* wk = (const float*)d_in[4]; const float* bk = (const float*)d_in[5];
  const float* wv = (const float*)d_in[6]; const float* bv = (const float*)d_in[7];
  const float* wo = (const float*)d_in[8]; const float* bo = (const float*)d_in[9];

  unsigned short* x_bf  = (unsigned short*)d_ws;
  unsigned short* wq_bf = x_bf + 8192 * 512;
  unsigned short* wk_bf = wq_bf + 512 * 512;
  unsigned short* wv_bf = wk_bf + 512 * 512;
  unsigned short* wo_bf = wv_bf + 512 * 512;
  unsigned short* q_bf  = wo_bf + 512 * 512;
  unsigned short* k_bf  = q_bf + 4194304;
  unsigned short* v_bf  = k_bf + 4194304;
  unsigned short* vt_bf = v_bf + 4194304;
  float* iqn   = (float*)(vt_bf + 4194304);
  float* ikn   = iqn + 65536;
  float* parts = ikn + 65536;

  float* out_f  = (float*)d_out;
  float* attn_o = out_f + 4194304;
  float* loss_o = attn_o + 67108864;

  cvt_kernel<<<4096, 256, 0, stream>>>(x, x_bf, 1048576);
  cvt_kernel<<<256, 256, 0, stream>>>(wq, wq_bf, 65536);
  cvt_kernel<<<256, 256, 0, stream>>>(wk, wk_bf, 65536);
  cvt_kernel<<<256, 256, 0, stream>>>(wv, wv_bf, 65536);
  cvt_kernel<<<256, 256, 0, stream>>>(wo, wo_bf, 65536);

  qkv_gemm_kernel<<<dim3(128, 24), 256, 0, stream>>>(
      x_bf, wq_bf, wk_bf, wv_bf, bq, bk, bv, q_bf, k_bf, v_bf, iqn, ikn);

  transpose_v_kernel<<<dim3(64, 16), 256, 0, stream>>>(v_bf, vt_bf);

  mega_attn_kernel<<<512, 256, 0, stream>>>(
      q_bf, k_bf, mask, iqn, ikn, vt_bf, wo_bf, bo, attn_o, out_f, parts);

  loss_reduce_kernel<<<1, 256, 0, stream>>>(parts, loss_o);
}